// Round 1
// baseline (274.495 us; speedup 1.0000x reference)
//
#include <hip/hip_runtime.h>

#define F 64
#define H 64
#define NT 256
#define TILE_ROWS 256     // per block per iteration: 4 waves x 64 rows
#define ITERS 4
#define ROWS_PER_BLOCK (TILE_ROWS * ITERS)   // 1024
#define WPAD 72   // LDS row stride in bf16 elems (144 B): 2-way bank alias on b64 reads (free)

typedef __bf16 bf16;
typedef __attribute__((ext_vector_type(8))) __bf16 bf16x8;
typedef __attribute__((ext_vector_type(4))) short s16x4;   // v4i16: one 16x16x16 bf16 A/B frag
typedef __attribute__((ext_vector_type(4))) float f32x4;

__device__ __forceinline__ float celu1(float v) {
    // CELU(alpha=1): x>0 ? x : exp(x)-1
    float e = __expf(v) - 1.0f;
    return v > 0.0f ? v : e;
}

__device__ __forceinline__ short bfb(float v) {
    bf16 h = (bf16)v;
    return __builtin_bit_cast(short, h);
}

// post-layer activation: celu on the 4 accum lanes, pack to a v4i16 bf16 frag.
// KEY INVARIANT: for v_mfma_f32_16x16x16_bf16 the D layout (col=lane&15,
// row=(lane>>4)*4+j) is IDENTICAL to the B layout (col=lane&15, k=(lane>>4)*4+j),
// so this frag is directly the next layer's B operand (kf = current m). No LDS
// round-trip for activations -- that round-trip (and its 7.3M bank-conflict
// cycles + pack/address VALU) was the R-session's residual overhead.
__device__ __forceinline__ s16x4 celu_frag(f32x4 a) {
    s16x4 r;
    r[0] = bfb(celu1(a[0]));
    r[1] = bfb(celu1(a[1]));
    r[2] = bfb(celu1(a[2]));
    r[3] = bfb(celu1(a[3]));
    return r;
}

#define MFMA16(A, B, C) __builtin_amdgcn_mfma_f32_16x16x16bf16_1k((A), (B), (C), 0, 0, 0)

// Block = one feature f x 1024 rows; 4 waves, each owns 64 rows per 256-row tile
// (4 independent 16-row MFMA chains per wave). All activations stay in registers
// as 16x16x16 fragments; both hidden-layer weight matrices live in LDS as v4i16
// A-frags read per (m,kf) with ds_read_b64 (2-way bank alias = free). Layer-in is
// a compensated rank-1 product (w_hi,w_lo,w_hi)x(x_hi,x_hi,x_lo) in k-slots 0..2.
// __launch_bounds__(256,4): cap 128 VGPRs. Live-set estimate ~120 (Bh 32 + Bh2 32
// at the crossover + weights frags 8 + acc 16 + persistent ~32). If VGPR_Count
// reads 64 and FETCH_SIZE jumps to 0.5-1 GB, that is the spill signature -> back
// off to (256,3).
__global__ __launch_bounds__(NT, 4) void mlp64(
    const float* __restrict__ x,      // [B,F]
    const float* __restrict__ w_in,
    const float* __restrict__ b_in,
    const float* __restrict__ w_hid,
    const float* __restrict__ b_hid,
    const float* __restrict__ w_out,
    const float* __restrict__ b_out,
    float* __restrict__ out,          // [B,F]
    int Btot)
{
    const int f    = blockIdx.x & (F - 1);
    const int blk  = blockIdx.x >> 6;
    const int row0 = blk * ROWS_PER_BLOCK;
    const int t    = threadIdx.x;
    const int lane = t & 63;
    const int l15  = lane & 15;
    const int q    = lane >> 4;
    const int wrow = (t >> 6) * 64;   // 64-row wave-private slice

    __shared__ __align__(16) bf16  wlds[2][H][WPAD];   // hidden weights [layer][out][in], 18.4 KB
    __shared__ __align__(16) float s_bias[3][H];

    // ---- stage both hidden layers' weights into LDS (fp32 -> bf16, once per block) ----
    for (int idx = t; idx < 1024; idx += NT) {
        const int l   = idx >> 9;
        const int row = (idx >> 3) & 63;
        const int ch  = idx & 7;
        const float* p = w_hid + (((size_t)l * F + f) << 12) + (row << 6) + (ch << 3);
        float4 a = *(const float4*)p, b = *(const float4*)(p + 4);
        bf16x8 v;
        v[0] = (bf16)a.x; v[1] = (bf16)a.y; v[2] = (bf16)a.z; v[3] = (bf16)a.w;
        v[4] = (bf16)b.x; v[5] = (bf16)b.y; v[6] = (bf16)b.z; v[7] = (bf16)b.w;
        *(bf16x8*)&wlds[l][row][ch * 8] = v;
    }
    if (t < H)           s_bias[0][t]         = b_in[f * H + t];
    else if (t < 2 * H)  s_bias[1][t - H]     = b_hid[(0 * F + f) * H + (t - H)];
    else if (t < 3 * H)  s_bias[2][t - 2 * H] = b_hid[(1 * F + f) * H + (t - 2 * H)];
    __syncthreads();

    // ---- layer-in A frags: quad 0 holds (w_hi, w_lo, w_hi, 0) in k-slots 0..3 ----
    s16x4 A1[4];
    #pragma unroll
    for (int m = 0; m < 4; ++m) {
        float w  = w_in[f * H + m * 16 + l15];
        bf16 hb  = (bf16)w;
        short hi = __builtin_bit_cast(short, hb);
        short lo = bfb(w - (float)hb);
        s16x4 v  = {};
        if (q == 0) { v[0] = hi; v[1] = lo; v[2] = hi; }
        A1[m] = v;
    }

    f32x4 wo4[4];
    #pragma unroll
    for (int m = 0; m < 4; ++m)
        wo4[m] = *(const f32x4*)(w_out + f * H + m * 16 + q * 4);
    const float bo = b_out[f];

    // strided 4B x loads; sharers are temporally adjacent blocks -> L2 hits
    float xc[4], xn[4];
    #pragma unroll
    for (int n = 0; n < 4; ++n)
        xc[n] = x[(size_t)(row0 + wrow + n * 16 + l15) * F + f];

    #pragma unroll 1
    for (int it = 0; it < ITERS; ++it) {
        const int rbase = row0 + it * TILE_ROWS + wrow;

        // B1 frags: quad 0 holds (x_hi, x_hi, x_lo, 0) in k-slots 0..3
        s16x4 B1[4];
        #pragma unroll
        for (int n = 0; n < 4; ++n) {
            bf16 hb  = (bf16)xc[n];
            short hh = __builtin_bit_cast(short, hb);
            short ll = bfb(xc[n] - (float)hb);
            s16x4 v  = {};
            if (q == 0) { v[0] = hh; v[1] = hh; v[2] = ll; }
            B1[n] = v;
        }
        #pragma unroll
        for (int n = 0; n < 4; ++n)
            xn[n] = (it + 1 < ITERS)
                  ? x[(size_t)(rbase + TILE_ROWS + n * 16 + l15) * F + f] : 0.0f;

        // ---- layer in->H: one K=16 MFMA per (m,n), D-frag -> B-frag of hidden-0 ----
        s16x4 Bh[4][4];                       // [n][kf]
        #pragma unroll
        for (int m = 0; m < 4; ++m) {
            f32x4 c0 = *(const f32x4*)&s_bias[0][m * 16 + q * 4];
            f32x4 a[4];
            #pragma unroll
            for (int n = 0; n < 4; ++n)
                a[n] = MFMA16(A1[m], B1[n], c0);
            #pragma unroll
            for (int n = 0; n < 4; ++n)
                Bh[n][m] = celu_frag(a[n]);
        }

        // ---- hidden layer 0 (LDS weight frags, K=16 chain of 4) ----
        s16x4 Bh2[4][4];
        #pragma unroll
        for (int m = 0; m < 4; ++m) {
            s16x4 Aw[4];
            #pragma unroll
            for (int kf = 0; kf < 4; ++kf)
                Aw[kf] = *(const s16x4*)&wlds[0][m * 16 + l15][kf * 16 + q * 4];
            f32x4 c0 = *(const f32x4*)&s_bias[1][m * 16 + q * 4];
            f32x4 a[4];
            #pragma unroll
            for (int n = 0; n < 4; ++n) {
                f32x4 acc = MFMA16(Aw[0], Bh[n][0], c0);
                acc = MFMA16(Aw[1], Bh[n][1], acc);
                acc = MFMA16(Aw[2], Bh[n][2], acc);
                acc = MFMA16(Aw[3], Bh[n][3], acc);
                a[n] = acc;
            }
            #pragma unroll
            for (int n = 0; n < 4; ++n)
                Bh2[n][m] = celu_frag(a[n]);
        }

        // ---- hidden layer 1 + output dot in registers (no cvt on last layer) ----
        {
            float s[4] = {0.0f, 0.0f, 0.0f, 0.0f};
            #pragma unroll
            for (int m = 0; m < 4; ++m) {
                s16x4 Aw[4];
                #pragma unroll
                for (int kf = 0; kf < 4; ++kf)
                    Aw[kf] = *(const s16x4*)&wlds[1][m * 16 + l15][kf * 16 + q * 4];
                f32x4 c0 = *(const f32x4*)&s_bias[2][m * 16 + q * 4];
                f32x4 a[4];
                #pragma unroll
                for (int n = 0; n < 4; ++n) {
                    f32x4 acc = MFMA16(Aw[0], Bh2[n][0], c0);
                    acc = MFMA16(Aw[1], Bh2[n][1], acc);
                    acc = MFMA16(Aw[2], Bh2[n][2], acc);
                    acc = MFMA16(Aw[3], Bh2[n][3], acc);
                    a[n] = acc;
                }
                #pragma unroll
                for (int n = 0; n < 4; ++n)
                    #pragma unroll
                    for (int rr = 0; rr < 4; ++rr)
                        s[n] = fmaf(celu1(a[n][rr]), wo4[m][rr], s[n]);
            }
            #pragma unroll
            for (int n = 0; n < 4; ++n) {
                s[n] += __shfl_xor(s[n], 16, 64);
                s[n] += __shfl_xor(s[n], 32, 64);
            }
            if (q == 0) {
                #pragma unroll
                for (int n = 0; n < 4; ++n)
                    out[(size_t)(rbase + n * 16 + l15) * F + f] = s[n] + bo;
            }
        }

        #pragma unroll
        for (int n = 0; n < 4; ++n) xc[n] = xn[n];
    }
}

extern "C" void kernel_launch(void* const* d_in, const int* in_sizes, int n_in,
                              void* d_out, int out_size, void* d_ws, size_t ws_size,
                              hipStream_t stream) {
    const float* x     = (const float*)d_in[0];
    const float* w_in  = (const float*)d_in[1];
    const float* b_in  = (const float*)d_in[2];
    const float* w_hid = (const float*)d_in[3];
    const float* b_hid = (const float*)d_in[4];
    const float* w_out = (const float*)d_in[5];
    const float* b_out = (const float*)d_in[6];
    float* out = (float*)d_out;

    const int Btot = in_sizes[0] / F;                       // 32768
    dim3 grid((unsigned)((Btot / ROWS_PER_BLOCK) * F));     // 2048 blocks
    dim3 block(NT);
    mlp64<<<grid, block, 0, stream>>>(x, w_in, b_in, w_hid, b_hid, w_out, b_out, out, Btot);
}

// Round 2
// 248.115 us; speedup vs baseline: 1.1063x; 1.1063x over previous
//
#include <hip/hip_runtime.h>

#define F 64
#define H 64
#define NT 256
#define TILE_ROWS 256     // per block per iteration: 4 waves x 64 rows
#define ITERS 4
#define ROWS_PER_BLOCK (TILE_ROWS * ITERS)   // 1024
#define WPAD 72   // LDS row stride in bf16 elems (144 B): 2-way bank alias on b64 reads (free)

typedef __bf16 bf16;
typedef __attribute__((ext_vector_type(8))) __bf16 bf16x8;
typedef __attribute__((ext_vector_type(4))) short s16x4;   // v4i16: one 16x16x16 bf16 A/B frag
typedef __attribute__((ext_vector_type(4))) float f32x4;

__device__ __forceinline__ float celu1(float v) {
    // CELU(alpha=1): x>0 ? x : exp(x)-1
    float e = __expf(v) - 1.0f;
    return v > 0.0f ? v : e;
}

__device__ __forceinline__ short bfb(float v) {
    bf16 h = (bf16)v;
    return __builtin_bit_cast(short, h);
}

// post-layer activation: celu on the 4 accum lanes, pack to a v4i16 bf16 frag.
// KEY INVARIANT: for v_mfma_f32_16x16x16_bf16 the D layout (col=lane&15,
// row=(lane>>4)*4+j) is IDENTICAL to the B layout (col=lane&15, k=(lane>>4)*4+j),
// so this frag is directly the next layer's B operand (kf = current m). No LDS
// round-trip for activations (R1 proved this: bank conflicts 7.34M -> 1.05M).
__device__ __forceinline__ s16x4 celu_frag(f32x4 a) {
    s16x4 r;
    r[0] = bfb(celu1(a[0]));
    r[1] = bfb(celu1(a[1]));
    r[2] = bfb(celu1(a[2]));
    r[3] = bfb(celu1(a[3]));
    return r;
}

#define MFMA16(A, B, C) __builtin_amdgcn_mfma_f32_16x16x16bf16_1k((A), (B), (C), 0, 0, 0)

// Block = one feature f x 1024 rows; 4 waves x 64 rows per 256-row tile.
// R1 POST-MORTEM: full 4-n fragment chaining at (256,4) spilled (VGPR=64 +
// FETCH 470MB signature) -- crossover live set Bh[4][4]+Bh2[4][4]=64 VGPRs + rest
// exceeded the 128 cap. FIX: process the wave's 64 rows as TWO sequential 32-row
// halves (#pragma unroll 1): crossover live = Bh[2][4]+Bh2[2][4] = 32 VGPRs, and
// w_out moved to LDS (broadcast reads). Peak live ~100 -> fits 128-reg cap at
// 4 blocks/CU. Cost: hidden weight frags re-read once more per tile (+32
// ds_read_b64, 2-way alias = free rate). If VGPR=64/FETCH>100MB again -> (256,3).
__global__ __launch_bounds__(NT, 4) void mlp64(
    const float* __restrict__ x,      // [B,F]
    const float* __restrict__ w_in,
    const float* __restrict__ b_in,
    const float* __restrict__ w_hid,
    const float* __restrict__ b_hid,
    const float* __restrict__ w_out,
    const float* __restrict__ b_out,
    float* __restrict__ out,          // [B,F]
    int Btot)
{
    const int f    = blockIdx.x & (F - 1);
    const int blk  = blockIdx.x >> 6;
    const int row0 = blk * ROWS_PER_BLOCK;
    const int t    = threadIdx.x;
    const int lane = t & 63;
    const int l15  = lane & 15;
    const int q    = lane >> 4;
    const int wrow = (t >> 6) * 64;   // 64-row wave-private slice

    __shared__ __align__(16) bf16  wlds[2][H][WPAD];   // hidden weights [layer][out][in], 18.4 KB
    __shared__ __align__(16) float s_bias[3][H];
    __shared__ __align__(16) float s_wout[H];

    // ---- stage both hidden layers' weights into LDS (fp32 -> bf16, once per block) ----
    for (int idx = t; idx < 1024; idx += NT) {
        const int l   = idx >> 9;
        const int row = (idx >> 3) & 63;
        const int ch  = idx & 7;
        const float* p = w_hid + (((size_t)l * F + f) << 12) + (row << 6) + (ch << 3);
        float4 a = *(const float4*)p, b = *(const float4*)(p + 4);
        bf16x8 v;
        v[0] = (bf16)a.x; v[1] = (bf16)a.y; v[2] = (bf16)a.z; v[3] = (bf16)a.w;
        v[4] = (bf16)b.x; v[5] = (bf16)b.y; v[6] = (bf16)b.z; v[7] = (bf16)b.w;
        *(bf16x8*)&wlds[l][row][ch * 8] = v;
    }
    if (t < H)           s_bias[0][t]         = b_in[f * H + t];
    else if (t < 2 * H)  s_bias[1][t - H]     = b_hid[(0 * F + f) * H + (t - H)];
    else if (t < 3 * H)  s_bias[2][t - 2 * H] = b_hid[(1 * F + f) * H + (t - 2 * H)];
    else                 s_wout[t - 3 * H]    = w_out[f * H + (t - 3 * H)];
    __syncthreads();

    // ---- layer-in A frags: quad 0 holds (w_hi, w_lo, w_hi, 0) in k-slots 0..3 ----
    s16x4 A1[4];
    #pragma unroll
    for (int m = 0; m < 4; ++m) {
        float w  = w_in[f * H + m * 16 + l15];
        bf16 hb  = (bf16)w;
        short hi = __builtin_bit_cast(short, hb);
        short lo = bfb(w - (float)hb);
        s16x4 v  = {};
        if (q == 0) { v[0] = hi; v[1] = lo; v[2] = hi; }
        A1[m] = v;
    }

    const float bo = b_out[f];

    // strided 4B x loads; sharers are temporally adjacent blocks -> L2 hits
    float xc[4], xn[4];
    #pragma unroll
    for (int n = 0; n < 4; ++n)
        xc[n] = x[(size_t)(row0 + wrow + n * 16 + l15) * F + f];

    #pragma unroll 1
    for (int it = 0; it < ITERS; ++it) {
        const int rbase = row0 + it * TILE_ROWS + wrow;

        #pragma unroll
        for (int n = 0; n < 4; ++n)
            xn[n] = (it + 1 < ITERS)
                  ? x[(size_t)(rbase + TILE_ROWS + n * 16 + l15) * F + f] : 0.0f;

        // ---- two sequential 32-row halves: caps crossover live set at 32 VGPRs ----
        #pragma unroll 1
        for (int half = 0; half < 2; ++half) {
            const int nb = half * 2;

            // B1 frags: quad 0 holds (x_hi, x_hi, x_lo, 0) in k-slots 0..3
            s16x4 B1[2];
            #pragma unroll
            for (int j = 0; j < 2; ++j) {
                float xv = xc[nb + j];
                bf16 hb  = (bf16)xv;
                short hh = __builtin_bit_cast(short, hb);
                short ll = bfb(xv - (float)hb);
                s16x4 v  = {};
                if (q == 0) { v[0] = hh; v[1] = hh; v[2] = ll; }
                B1[j] = v;
            }

            // ---- layer in->H: one K=16 MFMA per (m,j), D-frag -> B-frag of hidden-0 ----
            s16x4 Bh[2][4];                       // [j][kf]
            #pragma unroll
            for (int m = 0; m < 4; ++m) {
                f32x4 c0 = *(const f32x4*)&s_bias[0][m * 16 + q * 4];
                f32x4 a[2];
                #pragma unroll
                for (int j = 0; j < 2; ++j)
                    a[j] = MFMA16(A1[m], B1[j], c0);
                #pragma unroll
                for (int j = 0; j < 2; ++j)
                    Bh[j][m] = celu_frag(a[j]);
            }

            // ---- hidden layer 0 (LDS weight frags, K=16 chain of 4) ----
            s16x4 Bh2[2][4];
            #pragma unroll
            for (int m = 0; m < 4; ++m) {
                s16x4 Aw[4];
                #pragma unroll
                for (int kf = 0; kf < 4; ++kf)
                    Aw[kf] = *(const s16x4*)&wlds[0][m * 16 + l15][kf * 16 + q * 4];
                f32x4 c0 = *(const f32x4*)&s_bias[1][m * 16 + q * 4];
                f32x4 a[2];
                #pragma unroll
                for (int j = 0; j < 2; ++j) {
                    f32x4 acc = MFMA16(Aw[0], Bh[j][0], c0);
                    acc = MFMA16(Aw[1], Bh[j][1], acc);
                    acc = MFMA16(Aw[2], Bh[j][2], acc);
                    acc = MFMA16(Aw[3], Bh[j][3], acc);
                    a[j] = acc;
                }
                #pragma unroll
                for (int j = 0; j < 2; ++j)
                    Bh2[j][m] = celu_frag(a[j]);
            }

            // ---- hidden layer 1 + output dot in registers (no cvt on last layer) ----
            {
                float s[2] = {0.0f, 0.0f};
                #pragma unroll
                for (int m = 0; m < 4; ++m) {
                    s16x4 Aw[4];
                    #pragma unroll
                    for (int kf = 0; kf < 4; ++kf)
                        Aw[kf] = *(const s16x4*)&wlds[1][m * 16 + l15][kf * 16 + q * 4];
                    f32x4 c0 = *(const f32x4*)&s_bias[2][m * 16 + q * 4];
                    f32x4 wo = *(const f32x4*)&s_wout[m * 16 + q * 4];
                    f32x4 a[2];
                    #pragma unroll
                    for (int j = 0; j < 2; ++j) {
                        f32x4 acc = MFMA16(Aw[0], Bh2[j][0], c0);
                        acc = MFMA16(Aw[1], Bh2[j][1], acc);
                        acc = MFMA16(Aw[2], Bh2[j][2], acc);
                        acc = MFMA16(Aw[3], Bh2[j][3], acc);
                        a[j] = acc;
                    }
                    #pragma unroll
                    for (int j = 0; j < 2; ++j)
                        #pragma unroll
                        for (int rr = 0; rr < 4; ++rr)
                            s[j] = fmaf(celu1(a[j][rr]), wo[rr], s[j]);
                }
                #pragma unroll
                for (int j = 0; j < 2; ++j) {
                    s[j] += __shfl_xor(s[j], 16, 64);
                    s[j] += __shfl_xor(s[j], 32, 64);
                }
                if (q == 0) {
                    #pragma unroll
                    for (int j = 0; j < 2; ++j)
                        out[(size_t)(rbase + (nb + j) * 16 + l15) * F + f] = s[j] + bo;
                }
            }
        }

        #pragma unroll
        for (int n = 0; n < 4; ++n) xc[n] = xn[n];
    }
}

extern "C" void kernel_launch(void* const* d_in, const int* in_sizes, int n_in,
                              void* d_out, int out_size, void* d_ws, size_t ws_size,
                              hipStream_t stream) {
    const float* x     = (const float*)d_in[0];
    const float* w_in  = (const float*)d_in[1];
    const float* b_in  = (const float*)d_in[2];
    const float* w_hid = (const float*)d_in[3];
    const float* b_hid = (const float*)d_in[4];
    const float* w_out = (const float*)d_in[5];
    const float* b_out = (const float*)d_in[6];
    float* out = (float*)d_out;

    const int Btot = in_sizes[0] / F;                       // 32768
    dim3 grid((unsigned)((Btot / ROWS_PER_BLOCK) * F));     // 2048 blocks
    dim3 block(NT);
    mlp64<<<grid, block, 0, stream>>>(x, w_in, b_in, w_hid, b_hid, w_out, b_out, out, Btot);
}

// Round 3
// 227.758 us; speedup vs baseline: 1.2052x; 1.0894x over previous
//
#include <hip/hip_runtime.h>

#define F 64
#define H 64
#define NT 256
#define TILE_ROWS 256     // per block per iteration: 4 waves x 64 rows
#define ITERS 4
#define ROWS_PER_BLOCK (TILE_ROWS * ITERS)   // 1024
#define WPAD 72   // LDS row stride in bf16 elems (144 B): 2-way bank alias on b64 reads (free)

typedef __bf16 bf16;
typedef __attribute__((ext_vector_type(8))) __bf16 bf16x8;
typedef __attribute__((ext_vector_type(4))) short s16x4;   // v4i16: one 16x16x16 bf16 A/B frag
typedef __attribute__((ext_vector_type(4))) float f32x4;

__device__ __forceinline__ float celu1(float v) {
    // CELU(alpha=1): x>0 ? x : exp(x)-1
    float e = __expf(v) - 1.0f;
    return v > 0.0f ? v : e;
}

__device__ __forceinline__ short bfb(float v) {
    bf16 h = (bf16)v;
    return __builtin_bit_cast(short, h);
}

// post-layer activation: celu on the 4 accum lanes, pack to a v4i16 bf16 frag.
// KEY INVARIANT: for v_mfma_f32_16x16x16_bf16 the D layout (col=lane&15,
// row=(lane>>4)*4+j) is IDENTICAL to the B layout (col=lane&15, k=(lane>>4)*4+j),
// so this frag is directly the next layer's B operand (kf = current m). No LDS
// round-trip for activations (R1/R2 proved: bank conflicts 7.34M -> 1.05M).
__device__ __forceinline__ s16x4 celu_frag(f32x4 a) {
    s16x4 r;
    r[0] = bfb(celu1(a[0]));
    r[1] = bfb(celu1(a[1]));
    r[2] = bfb(celu1(a[2]));
    r[3] = bfb(celu1(a[3]));
    return r;
}

#define MFMA16(A, B, C) __builtin_amdgcn_mfma_f32_16x16x16bf16_1k((A), (B), (C), 0, 0, 0)

// Block = one feature f x 1024 rows; 4 waves x 64 rows per 256-row tile.
// REGISTER-PRESSURE HISTORY (do not regress):
//   R1 (256,4) full 4-n chains  -> SPILL (VGPR=64, FETCH 470MB)  274us
//   R2 (256,4) 2-half chains    -> SPILL (VGPR=64, FETCH 460MB)  248us
//   Hand-counted live set was <128 both times: hipcc's latency scheduler hoists
//   all 16 ds_read_b64 weight frags per layer ahead of the MFMA chains, and the
//   RA spills rather than re-schedule. (256,4)'s 128-reg cap is NOT reachable
//   for this structure. This version: (256,3), cap 170 -- the proven-no-spill
//   setting (R0: VGPR=84, FETCH=45MB) -- with full 4-n chaining for ILP.
// Spill signature to watch: reported VGPR_Count==64 + FETCH_SIZE >> 100MB.
__global__ __launch_bounds__(NT, 3) void mlp64(
    const float* __restrict__ x,      // [B,F]
    const float* __restrict__ w_in,
    const float* __restrict__ b_in,
    const float* __restrict__ w_hid,
    const float* __restrict__ b_hid,
    const float* __restrict__ w_out,
    const float* __restrict__ b_out,
    float* __restrict__ out,          // [B,F]
    int Btot)
{
    const int f    = blockIdx.x & (F - 1);
    const int blk  = blockIdx.x >> 6;
    const int row0 = blk * ROWS_PER_BLOCK;
    const int t    = threadIdx.x;
    const int lane = t & 63;
    const int l15  = lane & 15;
    const int q    = lane >> 4;
    const int wrow = (t >> 6) * 64;   // 64-row wave-private slice

    __shared__ __align__(16) bf16  wlds[2][H][WPAD];   // hidden weights [layer][out][in], 18.4 KB
    __shared__ __align__(16) float s_bias[3][H];
    __shared__ __align__(16) float s_wout[H];

    // ---- stage both hidden layers' weights into LDS (fp32 -> bf16, once per block) ----
    for (int idx = t; idx < 1024; idx += NT) {
        const int l   = idx >> 9;
        const int row = (idx >> 3) & 63;
        const int ch  = idx & 7;
        const float* p = w_hid + (((size_t)l * F + f) << 12) + (row << 6) + (ch << 3);
        float4 a = *(const float4*)p, b = *(const float4*)(p + 4);
        bf16x8 v;
        v[0] = (bf16)a.x; v[1] = (bf16)a.y; v[2] = (bf16)a.z; v[3] = (bf16)a.w;
        v[4] = (bf16)b.x; v[5] = (bf16)b.y; v[6] = (bf16)b.z; v[7] = (bf16)b.w;
        *(bf16x8*)&wlds[l][row][ch * 8] = v;
    }
    if (t < H)           s_bias[0][t]         = b_in[f * H + t];
    else if (t < 2 * H)  s_bias[1][t - H]     = b_hid[(0 * F + f) * H + (t - H)];
    else if (t < 3 * H)  s_bias[2][t - 2 * H] = b_hid[(1 * F + f) * H + (t - 2 * H)];
    else                 s_wout[t - 3 * H]    = w_out[f * H + (t - 3 * H)];
    __syncthreads();

    // ---- layer-in A frags: quad 0 holds (w_hi, w_lo, w_hi, 0) in k-slots 0..3 ----
    s16x4 A1[4];
    #pragma unroll
    for (int m = 0; m < 4; ++m) {
        float w  = w_in[f * H + m * 16 + l15];
        bf16 hb  = (bf16)w;
        short hi = __builtin_bit_cast(short, hb);
        short lo = bfb(w - (float)hb);
        s16x4 v  = {};
        if (q == 0) { v[0] = hi; v[1] = lo; v[2] = hi; }
        A1[m] = v;
    }

    const float bo = b_out[f];

    // strided 4B x loads; sharers are temporally adjacent blocks -> L2 hits
    float xc[4], xn[4];
    #pragma unroll
    for (int n = 0; n < 4; ++n)
        xc[n] = x[(size_t)(row0 + wrow + n * 16 + l15) * F + f];

    #pragma unroll 1
    for (int it = 0; it < ITERS; ++it) {
        const int rbase = row0 + it * TILE_ROWS + wrow;

        // B1 frags: quad 0 holds (x_hi, x_hi, x_lo, 0) in k-slots 0..3
        s16x4 B1[4];
        #pragma unroll
        for (int n = 0; n < 4; ++n) {
            bf16 hb  = (bf16)xc[n];
            short hh = __builtin_bit_cast(short, hb);
            short ll = bfb(xc[n] - (float)hb);
            s16x4 v  = {};
            if (q == 0) { v[0] = hh; v[1] = hh; v[2] = ll; }
            B1[n] = v;
        }
        #pragma unroll
        for (int n = 0; n < 4; ++n)
            xn[n] = (it + 1 < ITERS)
                  ? x[(size_t)(rbase + TILE_ROWS + n * 16 + l15) * F + f] : 0.0f;

        // ---- layer in->H: one K=16 MFMA per (m,n), D-frag -> B-frag of hidden-0 ----
        s16x4 Bh[4][4];                       // [n][kf]
        #pragma unroll
        for (int m = 0; m < 4; ++m) {
            f32x4 c0 = *(const f32x4*)&s_bias[0][m * 16 + q * 4];
            f32x4 a[4];
            #pragma unroll
            for (int n = 0; n < 4; ++n)
                a[n] = MFMA16(A1[m], B1[n], c0);
            #pragma unroll
            for (int n = 0; n < 4; ++n)
                Bh[n][m] = celu_frag(a[n]);
        }

        // ---- hidden layer 0 (LDS weight frags, K=16 chain of 4) ----
        s16x4 Bh2[4][4];
        #pragma unroll
        for (int m = 0; m < 4; ++m) {
            s16x4 Aw[4];
            #pragma unroll
            for (int kf = 0; kf < 4; ++kf)
                Aw[kf] = *(const s16x4*)&wlds[0][m * 16 + l15][kf * 16 + q * 4];
            f32x4 c0 = *(const f32x4*)&s_bias[1][m * 16 + q * 4];
            f32x4 a[4];
            #pragma unroll
            for (int n = 0; n < 4; ++n) {
                f32x4 acc = MFMA16(Aw[0], Bh[n][0], c0);
                acc = MFMA16(Aw[1], Bh[n][1], acc);
                acc = MFMA16(Aw[2], Bh[n][2], acc);
                acc = MFMA16(Aw[3], Bh[n][3], acc);
                a[n] = acc;
            }
            #pragma unroll
            for (int n = 0; n < 4; ++n)
                Bh2[n][m] = celu_frag(a[n]);
        }

        // ---- hidden layer 1 + output dot in registers (no cvt on last layer) ----
        {
            float s[4] = {0.0f, 0.0f, 0.0f, 0.0f};
            #pragma unroll
            for (int m = 0; m < 4; ++m) {
                s16x4 Aw[4];
                #pragma unroll
                for (int kf = 0; kf < 4; ++kf)
                    Aw[kf] = *(const s16x4*)&wlds[1][m * 16 + l15][kf * 16 + q * 4];
                f32x4 c0 = *(const f32x4*)&s_bias[2][m * 16 + q * 4];
                f32x4 wo = *(const f32x4*)&s_wout[m * 16 + q * 4];
                f32x4 a[4];
                #pragma unroll
                for (int n = 0; n < 4; ++n) {
                    f32x4 acc = MFMA16(Aw[0], Bh2[n][0], c0);
                    acc = MFMA16(Aw[1], Bh2[n][1], acc);
                    acc = MFMA16(Aw[2], Bh2[n][2], acc);
                    acc = MFMA16(Aw[3], Bh2[n][3], acc);
                    a[n] = acc;
                }
                #pragma unroll
                for (int n = 0; n < 4; ++n)
                    #pragma unroll
                    for (int rr = 0; rr < 4; ++rr)
                        s[n] = fmaf(celu1(a[n][rr]), wo[rr], s[n]);
            }
            #pragma unroll
            for (int n = 0; n < 4; ++n) {
                s[n] += __shfl_xor(s[n], 16, 64);
                s[n] += __shfl_xor(s[n], 32, 64);
            }
            if (q == 0) {
                #pragma unroll
                for (int n = 0; n < 4; ++n)
                    out[(size_t)(rbase + n * 16 + l15) * F + f] = s[n] + bo;
            }
        }

        #pragma unroll
        for (int n = 0; n < 4; ++n) xc[n] = xn[n];
    }
}

extern "C" void kernel_launch(void* const* d_in, const int* in_sizes, int n_in,
                              void* d_out, int out_size, void* d_ws, size_t ws_size,
                              hipStream_t stream) {
    const float* x     = (const float*)d_in[0];
    const float* w_in  = (const float*)d_in[1];
    const float* b_in  = (const float*)d_in[2];
    const float* w_hid = (const float*)d_in[3];
    const float* b_hid = (const float*)d_in[4];
    const float* w_out = (const float*)d_in[5];
    const float* b_out = (const float*)d_in[6];
    float* out = (float*)d_out;

    const int Btot = in_sizes[0] / F;                       // 32768
    dim3 grid((unsigned)((Btot / ROWS_PER_BLOCK) * F));     // 2048 blocks
    dim3 block(NT);
    mlp64<<<grid, block, 0, stream>>>(x, w_in, b_in, w_hid, b_hid, w_out, b_out, out, Btot);
}

// Round 4
// 160.611 us; speedup vs baseline: 1.7091x; 1.4181x over previous
//
#include <hip/hip_runtime.h>

#define F 64
#define H 64
#define NT 256
#define TILE_ROWS 256     // per block per iteration: 4 waves x 64 rows
#define ITERS 4
#define ROWS_PER_BLOCK (TILE_ROWS * ITERS)   // 1024
#define WPAD 72   // LDS row stride in bf16 elems (144 B): 2-way bank alias on b64 reads (free)

typedef __bf16 bf16;
typedef __attribute__((ext_vector_type(8))) __bf16 bf16x8;
typedef __attribute__((ext_vector_type(4))) short s16x4;   // v4i16: one 16x16x16 bf16 A/B frag
typedef __attribute__((ext_vector_type(4))) float f32x4;

__device__ __forceinline__ float celu1(float v) {
    // CELU(alpha=1): x>0 ? x : exp(x)-1
    float e = __expf(v) - 1.0f;
    return v > 0.0f ? v : e;
}

__device__ __forceinline__ short bfb(float v) {
    bf16 h = (bf16)v;
    return __builtin_bit_cast(short, h);
}

// post-layer activation: celu on the 4 accum lanes, pack to a v4i16 bf16 frag.
// KEY INVARIANT: for v_mfma_f32_16x16x16_bf16 the D layout (col=lane&15,
// row=(lane>>4)*4+j) is IDENTICAL to the B layout (col=lane&15, k=(lane>>4)*4+j),
// so this frag is directly the next layer's B operand (kf = current m). No LDS
// round-trip for activations (R1/R2 proved: bank conflicts 7.34M -> 1.05M).
__device__ __forceinline__ s16x4 celu_frag(f32x4 a) {
    s16x4 r;
    r[0] = bfb(celu1(a[0]));
    r[1] = bfb(celu1(a[1]));
    r[2] = bfb(celu1(a[2]));
    r[3] = bfb(celu1(a[3]));
    return r;
}

#define MFMA16(A, B, C) __builtin_amdgcn_mfma_f32_16x16x16bf16_1k((A), (B), (C), 0, 0, 0)
#define SCHED_WALL()    __builtin_amdgcn_sched_barrier(0)

// Block = one feature f x 1024 rows; 4 waves x 64 rows per 256-row tile.
// REGISTER-PRESSURE HISTORY (do not regress):
//   R1 (256,4) 4-n chains          -> SPILL (FETCH 470MB, WRITE 325MB)  274us
//   R2 (256,4) 2-half chains       -> SPILL (FETCH 460MB, WRITE 255MB)  248us
//   R3 (256,3) 4-n chains          -> STILL SPILLS (FETCH 254MB, WRITE 223MB) 176us
//     Diagnosis: hidden-1 stage has NO data dep on hidden-0, so the latency
//     scheduler hoists wlds[1] ds_reads + addr math above the hidden-0 chains,
//     stacking both stages' live sets (Bh 32 + Bh2 32 + Aw 32 + accums) -> RA spills.
//   R4 (this): sched_barrier(0) WALLS between the three layer stages pin the
//     stage live-ranges apart. Peak live ~130 < 170 cap at (256,3).
// Spill signature to watch: WRITE_SIZE >> 100MB (out-writes alone are ~98MB).
__global__ __launch_bounds__(NT, 3) void mlp64(
    const float* __restrict__ x,      // [B,F]
    const float* __restrict__ w_in,
    const float* __restrict__ b_in,
    const float* __restrict__ w_hid,
    const float* __restrict__ b_hid,
    const float* __restrict__ w_out,
    const float* __restrict__ b_out,
    float* __restrict__ out,          // [B,F]
    int Btot)
{
    const int f    = blockIdx.x & (F - 1);
    const int blk  = blockIdx.x >> 6;
    const int row0 = blk * ROWS_PER_BLOCK;
    const int t    = threadIdx.x;
    const int lane = t & 63;
    const int l15  = lane & 15;
    const int q    = lane >> 4;
    const int wrow = (t >> 6) * 64;   // 64-row wave-private slice

    __shared__ __align__(16) bf16  wlds[2][H][WPAD];   // hidden weights [layer][out][in], 18.4 KB
    __shared__ __align__(16) float s_bias[3][H];
    __shared__ __align__(16) float s_wout[H];

    // ---- stage both hidden layers' weights into LDS (fp32 -> bf16, once per block) ----
    for (int idx = t; idx < 1024; idx += NT) {
        const int l   = idx >> 9;
        const int row = (idx >> 3) & 63;
        const int ch  = idx & 7;
        const float* p = w_hid + (((size_t)l * F + f) << 12) + (row << 6) + (ch << 3);
        float4 a = *(const float4*)p, b = *(const float4*)(p + 4);
        bf16x8 v;
        v[0] = (bf16)a.x; v[1] = (bf16)a.y; v[2] = (bf16)a.z; v[3] = (bf16)a.w;
        v[4] = (bf16)b.x; v[5] = (bf16)b.y; v[6] = (bf16)b.z; v[7] = (bf16)b.w;
        *(bf16x8*)&wlds[l][row][ch * 8] = v;
    }
    if (t < H)           s_bias[0][t]         = b_in[f * H + t];
    else if (t < 2 * H)  s_bias[1][t - H]     = b_hid[(0 * F + f) * H + (t - H)];
    else if (t < 3 * H)  s_bias[2][t - 2 * H] = b_hid[(1 * F + f) * H + (t - 2 * H)];
    else                 s_wout[t - 3 * H]    = w_out[f * H + (t - 3 * H)];
    __syncthreads();

    // ---- layer-in A frags: quad 0 holds (w_hi, w_lo, w_hi, 0) in k-slots 0..3 ----
    s16x4 A1[4];
    #pragma unroll
    for (int m = 0; m < 4; ++m) {
        float w  = w_in[f * H + m * 16 + l15];
        bf16 hb  = (bf16)w;
        short hi = __builtin_bit_cast(short, hb);
        short lo = bfb(w - (float)hb);
        s16x4 v  = {};
        if (q == 0) { v[0] = hi; v[1] = lo; v[2] = hi; }
        A1[m] = v;
    }

    const float bo = b_out[f];

    // strided 4B x loads; sharers are temporally adjacent blocks -> L2 hits
    float xc[4], xn[4];
    #pragma unroll
    for (int n = 0; n < 4; ++n)
        xc[n] = x[(size_t)(row0 + wrow + n * 16 + l15) * F + f];

    #pragma unroll 1
    for (int it = 0; it < ITERS; ++it) {
        const int rbase = row0 + it * TILE_ROWS + wrow;

        // B1 frags: quad 0 holds (x_hi, x_hi, x_lo, 0) in k-slots 0..3
        s16x4 B1[4];
        #pragma unroll
        for (int n = 0; n < 4; ++n) {
            bf16 hb  = (bf16)xc[n];
            short hh = __builtin_bit_cast(short, hb);
            short ll = bfb(xc[n] - (float)hb);
            s16x4 v  = {};
            if (q == 0) { v[0] = hh; v[1] = hh; v[2] = ll; }
            B1[n] = v;
        }
        #pragma unroll
        for (int n = 0; n < 4; ++n)
            xn[n] = (it + 1 < ITERS)
                  ? x[(size_t)(rbase + TILE_ROWS + n * 16 + l15) * F + f] : 0.0f;

        // ---- layer in->H: one K=16 MFMA per (m,n), D-frag -> B-frag of hidden-0 ----
        s16x4 Bh[4][4];                       // [n][kf]
        #pragma unroll
        for (int m = 0; m < 4; ++m) {
            f32x4 c0 = *(const f32x4*)&s_bias[0][m * 16 + q * 4];
            f32x4 a[4];
            #pragma unroll
            for (int n = 0; n < 4; ++n)
                a[n] = MFMA16(A1[m], B1[n], c0);
            #pragma unroll
            for (int n = 0; n < 4; ++n)
                Bh[n][m] = celu_frag(a[n]);
        }

        SCHED_WALL();   // keep hidden-0's ds_reads/live-ranges out of layer-in

        // ---- hidden layer 0 (LDS weight frags, K=16 chain of 4) ----
        s16x4 Bh2[4][4];
        #pragma unroll
        for (int m = 0; m < 4; ++m) {
            s16x4 Aw[4];
            #pragma unroll
            for (int kf = 0; kf < 4; ++kf)
                Aw[kf] = *(const s16x4*)&wlds[0][m * 16 + l15][kf * 16 + q * 4];
            f32x4 c0 = *(const f32x4*)&s_bias[1][m * 16 + q * 4];
            f32x4 a[4];
            #pragma unroll
            for (int n = 0; n < 4; ++n) {
                f32x4 acc = MFMA16(Aw[0], Bh[n][0], c0);
                acc = MFMA16(Aw[1], Bh[n][1], acc);
                acc = MFMA16(Aw[2], Bh[n][2], acc);
                acc = MFMA16(Aw[3], Bh[n][3], acc);
                a[n] = acc;
            }
            #pragma unroll
            for (int n = 0; n < 4; ++n)
                Bh2[n][m] = celu_frag(a[n]);
        }

        SCHED_WALL();   // keep hidden-1's ds_reads/live-ranges out of hidden-0

        // ---- hidden layer 1 + output dot in registers (no cvt on last layer) ----
        {
            float s[4] = {0.0f, 0.0f, 0.0f, 0.0f};
            #pragma unroll
            for (int m = 0; m < 4; ++m) {
                s16x4 Aw[4];
                #pragma unroll
                for (int kf = 0; kf < 4; ++kf)
                    Aw[kf] = *(const s16x4*)&wlds[1][m * 16 + l15][kf * 16 + q * 4];
                f32x4 c0 = *(const f32x4*)&s_bias[2][m * 16 + q * 4];
                f32x4 wo = *(const f32x4*)&s_wout[m * 16 + q * 4];
                f32x4 a[4];
                #pragma unroll
                for (int n = 0; n < 4; ++n) {
                    f32x4 acc = MFMA16(Aw[0], Bh2[n][0], c0);
                    acc = MFMA16(Aw[1], Bh2[n][1], acc);
                    acc = MFMA16(Aw[2], Bh2[n][2], acc);
                    acc = MFMA16(Aw[3], Bh2[n][3], acc);
                    a[n] = acc;
                }
                #pragma unroll
                for (int n = 0; n < 4; ++n)
                    #pragma unroll
                    for (int rr = 0; rr < 4; ++rr)
                        s[n] = fmaf(celu1(a[n][rr]), wo[rr], s[n]);
            }
            #pragma unroll
            for (int n = 0; n < 4; ++n) {
                s[n] += __shfl_xor(s[n], 16, 64);
                s[n] += __shfl_xor(s[n], 32, 64);
            }
            if (q == 0) {
                #pragma unroll
                for (int n = 0; n < 4; ++n)
                    out[(size_t)(rbase + n * 16 + l15) * F + f] = s[n] + bo;
            }
        }

        SCHED_WALL();   // keep next iteration's work out of this one's epilogue

        #pragma unroll
        for (int n = 0; n < 4; ++n) xc[n] = xn[n];
    }
}

extern "C" void kernel_launch(void* const* d_in, const int* in_sizes, int n_in,
                              void* d_out, int out_size, void* d_ws, size_t ws_size,
                              hipStream_t stream) {
    const float* x     = (const float*)d_in[0];
    const float* w_in  = (const float*)d_in[1];
    const float* b_in  = (const float*)d_in[2];
    const float* w_hid = (const float*)d_in[3];
    const float* b_hid = (const float*)d_in[4];
    const float* w_out = (const float*)d_in[5];
    const float* b_out = (const float*)d_in[6];
    float* out = (float*)d_out;

    const int Btot = in_sizes[0] / F;                       // 32768
    dim3 grid((unsigned)((Btot / ROWS_PER_BLOCK) * F));     // 2048 blocks
    dim3 block(NT);
    mlp64<<<grid, block, 0, stream>>>(x, w_in, b_in, w_hid, b_hid, w_out, b_out, out, Btot);
}